// Round 5
// baseline (164.301 us; speedup 1.0000x reference)
//
#include <hip/hip_runtime.h>
#include <math.h>

#define BB 64
#define WW 128
#define FF 64
#define HH 4
#define OW 128
#define HO 512

// ---------------------------------------------------------------------------
// Kernel 1: projections. Grid 1024 = b(64) x rt(16). rt<8 -> fs family,
// rt>=8 -> fd family; within family: h = (rt&7)>>1, dhalf = rt&1.
// Block 256 = 4 waves; wave owns 16 rows (d), lane = f/i. x[b] staged in LDS
// (stride-1 b32 reads, free); W rows are lane-invariant addresses -> scalar
// s_load, off the VALU/VMEM pipes. FMA-issue-bound by construction.
// Outputs: fs [b][h][d][i] (direct, coalesced), and via in-LDS transpose
// (reusing the x buffer): fs_im [b][h][i][d] / fd_t [b][h][j][d].
// ---------------------------------------------------------------------------
__global__ __launch_bounds__(256, 4) void gat_proj(
    const float* __restrict__ x,     // [B][W][F]
    const float* __restrict__ Wsrc,  // [512][128]
    const float* __restrict__ bsrc,
    const float* __restrict__ Wdst,
    const float* __restrict__ bdst,
    float* __restrict__ fs,          // [B][H][128][64]
    float* __restrict__ fs_im,       // [B][H][64][128]
    float* __restrict__ fd_t)        // [B][H][64][128]
{
    __shared__ float xl[WW * FF];        // 32 KB; reused as transpose buffer
    float* tr = xl;                      // tr[i][68], 64*68 floats (17 KB)

    const int b  = blockIdx.x >> 4;
    const int rt = blockIdx.x & 15;
    const bool is_src = rt < 8;
    const int h     = (rt & 7) >> 1;
    const int dhalf = rt & 1;

    const float* Wm = is_src ? Wsrc : Wdst;
    const float* bm = is_src ? bsrc : bdst;

    const int t    = threadIdx.x;
    const int wv   = t >> 6;
    const int lane = t & 63;

    // ---- stage x[b] (32 KB, coalesced float4) ----
    {
        const float4* xs = (const float4*)(x + (size_t)b * (WW * FF));
        float4* xd = (float4*)xl;
        #pragma unroll
        for (int p = 0; p < 8; ++p)
            xd[p * 256 + t] = xs[p * 256 + t];
    }
    __syncthreads();

    const int d0   = dhalf * 64 + wv * 16;   // d within head
    const int row0 = h * OW + d0;            // row within W matrix
    const float* wb = Wm + (size_t)row0 * WW;

    float acc[16] = {};
    for (int k0 = 0; k0 < WW; k0 += 4) {
        float xv0 = xl[(k0 + 0) * FF + lane];
        float xv1 = xl[(k0 + 1) * FF + lane];
        float xv2 = xl[(k0 + 2) * FF + lane];
        float xv3 = xl[(k0 + 3) * FF + lane];
        #pragma unroll
        for (int rr = 0; rr < 16; ++rr) {
            float4 wr = *(const float4*)&wb[rr * WW + k0];   // uniform -> s_load
            acc[rr] = fmaf(xv0, wr.x, acc[rr]);
            acc[rr] = fmaf(xv1, wr.y, acc[rr]);
            acc[rr] = fmaf(xv2, wr.z, acc[rr]);
            acc[rr] = fmaf(xv3, wr.w, acc[rr]);
        }
    }
    #pragma unroll
    for (int rr = 0; rr < 16; ++rr)
        acc[rr] += bm[row0 + rr];            // uniform scalar load

    const size_t bh = (size_t)b * HH + h;

    // ---- fs family: direct [d][i] store, coalesced ----
    if (is_src) {
        #pragma unroll
        for (int rr = 0; rr < 16; ++rr)
            fs[(bh * OW + d0 + rr) * FF + lane] = acc[rr];
    }

    // ---- transpose via LDS (x buffer dead now) -> [i][d] store ----
    __syncthreads();
    #pragma unroll
    for (int q = 0; q < 4; ++q) {
        float4 v = { acc[4*q+0], acc[4*q+1], acc[4*q+2], acc[4*q+3] };
        *(float4*)&tr[lane * 68 + wv * 16 + q * 4] = v;   // one-time, ~8-way ok
    }
    __syncthreads();
    float* dstT = (is_src ? fs_im : fd_t) + bh * (FF * OW) + dhalf * 64;
    const int i  = t >> 2;
    const int q4 = (t & 3) * 4;
    #pragma unroll
    for (int ii = 0; ii < 4; ++ii) {
        float4 v = *(const float4*)&tr[i * 68 + q4 + ii * 16];
        *(float4*)&dstT[(size_t)i * OW + q4 + ii * 16] = v;   // 64B segments
    }
}

// ---------------------------------------------------------------------------
// Kernel 2: scores + edge-softmax + aggregation. Grid 1024 = (b, h, jq of 16).
// Block 256 = 4 waves; LDS 40.2 KB -> 4 blocks/CU (16 waves/CU).
// Phase 1: lane = i; fs rows coalesced b32 from global (L1-hot slice),
//          fd_t rows = single b128 broadcast; lrelu*a = 0.6a*s + 0.4a*|s|.
//          Scores written TRANSPOSED to St[jl][i] (stride-1, conflict-free).
// Phase 2: strip-reduced max/exp/sum on St in place. No shuffles.
// Phase 3: lane = d (2 halves); fs_im slice staged in LDS, stride-1 b32 reads;
//          P = b128 broadcasts from St. VALU-bound. Coalesced [j][d] store.
// ---------------------------------------------------------------------------
__global__ __launch_bounds__(256, 4) void gat_attn(
    const float* __restrict__ fs,     // [B][H][128][64]
    const float* __restrict__ fs_im,  // [B][H][64][128]
    const float* __restrict__ fd_t,   // [B][H][64][128]
    const float* __restrict__ attn,   // [H][128]
    float* __restrict__ ws2)          // [B][H][64 j][128 d]
{
    __shared__ float fsl[FF * OW];       // 32 KB  [i][d]
    __shared__ float St[16 * 68];        // 4.25 KB scores -> P, [jl][i]
    __shared__ float A6[OW], B4[OW];     // 1 KB
    __shared__ float redmax[16][16];     // 1 KB
    __shared__ float redsum[16][16];     // 1 KB
    __shared__ float invl[16];

    const int bx = blockIdx.x;
    const int jq = bx & 3;
    const int h  = (bx >> 2) & 3;
    const int b  = bx >> 4;
    const size_t bh = (size_t)b * HH + h;

    const int t    = threadIdx.x;
    const int wv   = t >> 6;
    const int lane = t & 63;

    // ---- stage fs_im slice (32 KB) + folded attn coefficients ----
    {
        const float4* s = (const float4*)(fs_im + bh * (FF * OW));
        float4* d4 = (float4*)fsl;
        #pragma unroll
        for (int p = 0; p < 8; ++p)
            d4[p * 256 + t] = s[p * 256 + t];
        if (t < 128) {
            float a = attn[h * OW + t];
            A6[t] = 0.6f * a;
            B4[t] = 0.4f * a;
        }
    }
    __syncthreads();

    // ---- phase 1: scores; wave wv handles j = jq*16 + wv*4 .. +3, lane = i ----
    const float* fsg = fs   + bh * (OW * FF);     // [d][i]
    const float* fdg = fd_t + bh * (FF * OW);     // [j][d]
    const int jl0 = wv * 4;
    const int jbase = jq * 16 + jl0;
    float sc[4] = {0.0f, 0.0f, 0.0f, 0.0f};
    for (int c = 0; c < 32; ++c) {
        const int d0 = c * 4;
        float f0 = fsg[(d0 + 0) * FF + lane];     // coalesced, L1-hot
        float f1 = fsg[(d0 + 1) * FF + lane];
        float f2 = fsg[(d0 + 2) * FF + lane];
        float f3 = fsg[(d0 + 3) * FF + lane];
        float4 a6 = *(const float4*)&A6[d0];
        float4 b4 = *(const float4*)&B4[d0];
        #pragma unroll
        for (int jj = 0; jj < 4; ++jj) {
            float4 fdv = *(const float4*)&fdg[(size_t)(jbase + jj) * OW + d0]; // bcast
            float s, r = sc[jj];
            s = f0 + fdv.x; r = fmaf(a6.x, s, fmaf(b4.x, fabsf(s), r));
            s = f1 + fdv.y; r = fmaf(a6.y, s, fmaf(b4.y, fabsf(s), r));
            s = f2 + fdv.z; r = fmaf(a6.z, s, fmaf(b4.z, fabsf(s), r));
            s = f3 + fdv.w; r = fmaf(a6.w, s, fmaf(b4.w, fabsf(s), r));
            sc[jj] = r;
        }
    }
    #pragma unroll
    for (int jj = 0; jj < 4; ++jj)
        St[(jl0 + jj) * 68 + lane] = sc[jj];      // stride-1, conflict-free
    __syncthreads();

    // ---- phase 2: softmax over i per column j (strips of 4 i) ----
    {
        const int j = t & 15, st = t >> 4;
        const float* row = &St[j * 68 + st * 4];
        redmax[st][j] = fmaxf(fmaxf(row[0], row[1]), fmaxf(row[2], row[3]));
    }
    __syncthreads();
    {
        const int j = t & 15, st = t >> 4;
        float mj = redmax[0][j];
        #pragma unroll
        for (int s2 = 1; s2 < 16; ++s2) mj = fmaxf(mj, redmax[s2][j]);
        float* row = &St[j * 68 + st * 4];
        float e0 = __expf(row[0] - mj);
        float e1 = __expf(row[1] - mj);
        float e2 = __expf(row[2] - mj);
        float e3 = __expf(row[3] - mj);
        float4 ev = {e0, e1, e2, e3};
        *(float4*)row = ev;                       // P in place
        redsum[st][j] = e0 + e1 + e2 + e3;
    }
    __syncthreads();
    if (t < 16) {
        float l = 0.0f;
        #pragma unroll
        for (int s2 = 0; s2 < 16; ++s2) l += redsum[s2][t];
        invl[t] = 0.25f / l;                      // head-mean folded
    }
    __syncthreads();

    // ---- phase 3: aggregation; lane = d (two halves), wave's 4 j ----
    float ag[4][2] = {};
    for (int ic = 0; ic < FF; ic += 4) {
        float4 p0 = *(const float4*)&St[(jl0 + 0) * 68 + ic];   // bcast b128
        float4 p1 = *(const float4*)&St[(jl0 + 1) * 68 + ic];
        float4 p2 = *(const float4*)&St[(jl0 + 2) * 68 + ic];
        float4 p3 = *(const float4*)&St[(jl0 + 3) * 68 + ic];
        #pragma unroll
        for (int ii = 0; ii < 4; ++ii) {
            float fa = fsl[(ic + ii) * OW + lane];        // stride-1, free
            float fb = fsl[(ic + ii) * OW + 64 + lane];
            ag[0][0] = fmaf(((const float*)&p0)[ii], fa, ag[0][0]);
            ag[0][1] = fmaf(((const float*)&p0)[ii], fb, ag[0][1]);
            ag[1][0] = fmaf(((const float*)&p1)[ii], fa, ag[1][0]);
            ag[1][1] = fmaf(((const float*)&p1)[ii], fb, ag[1][1]);
            ag[2][0] = fmaf(((const float*)&p2)[ii], fa, ag[2][0]);
            ag[2][1] = fmaf(((const float*)&p2)[ii], fb, ag[2][1]);
            ag[3][0] = fmaf(((const float*)&p3)[ii], fa, ag[3][0]);
            ag[3][1] = fmaf(((const float*)&p3)[ii], fb, ag[3][1]);
        }
    }
    float* wout = ws2 + bh * (FF * OW);
    #pragma unroll
    for (int jj = 0; jj < 4; ++jj) {
        float ivv = invl[jl0 + jj];
        wout[(size_t)(jbase + jj) * OW + lane]      = ag[jj][0] * ivv;  // coalesced
        wout[(size_t)(jbase + jj) * OW + 64 + lane] = ag[jj][1] * ivv;
    }
}

// ---------------------------------------------------------------------------
// Kernel 3: head-sum + transpose -> out[b][d][f]. Grid 256 = (b, jg of 16).
// ---------------------------------------------------------------------------
__global__ __launch_bounds__(256, 4) void gat_reduce(
    const float* __restrict__ ws2,   // [B][H][64 j][128 d]
    float* __restrict__ out)         // [B][128 d][64 f]
{
    __shared__ float tl[16][132];
    const int b  = blockIdx.x >> 2;
    const int jg = blockIdx.x & 3;
    const int t  = threadIdx.x;

    const float* base = ws2 + ((size_t)b * HH * FF + jg * 16) * OW;
    #pragma unroll
    for (int p = 0; p < 2; ++p) {
        int idx = p * 256 + t;               // float4 idx in [16 j][32 q]
        int j = idx >> 5, q = idx & 31;
        const float* src = base + (size_t)j * OW + q * 4;
        float4 s0 = *(const float4*)(src);
        float4 s1 = *(const float4*)(src + (size_t)FF * OW);
        float4 s2 = *(const float4*)(src + (size_t)2 * FF * OW);
        float4 s3 = *(const float4*)(src + (size_t)3 * FF * OW);
        float4 o;
        o.x = s0.x + s1.x + s2.x + s3.x;
        o.y = s0.y + s1.y + s2.y + s3.y;
        o.z = s0.z + s1.z + s2.z + s3.z;
        o.w = s0.w + s1.w + s2.w + s3.w;
        *(float4*)&tl[j][q * 4] = o;
    }
    __syncthreads();
    #pragma unroll
    for (int it = 0; it < 8; ++it) {
        int idx = it * 256 + t;
        int j = idx & 15, d = idx >> 4;
        out[((size_t)b * OW + d) * FF + jg * 16 + j] = tl[j][d];
    }
}

// ---------------------------------------------------------------------------
extern "C" void kernel_launch(void* const* d_in, const int* in_sizes, int n_in,
                              void* d_out, int out_size, void* d_ws, size_t ws_size,
                              hipStream_t stream) {
    const float* x    = (const float*)d_in[0];
    const float* Wsrc = (const float*)d_in[1];
    const float* bsrc = (const float*)d_in[2];
    const float* Wdst = (const float*)d_in[3];
    const float* bdst = (const float*)d_in[4];
    const float* attn = (const float*)d_in[5];
    float* out = (float*)d_out;

    const size_t SL = (size_t)BB * HH * FF * OW;      // 2M floats = 8 MB
    float* fs    = (float*)d_ws;
    float* fs_im = fs    + SL;
    float* fd_t  = fs_im + SL;
    float* ws2   = fd_t  + SL;

    gat_proj  <<<BB * 16, 256, 0, stream>>>(x, Wsrc, bsrc, Wdst, bdst, fs, fs_im, fd_t);
    gat_attn  <<<BB * HH * 4, 256, 0, stream>>>(fs, fs_im, fd_t, attn, ws2);
    gat_reduce<<<BB * 4, 256, 0, stream>>>(ws2, out);
}

// Round 6
// 117.574 us; speedup vs baseline: 1.3974x; 1.3974x over previous
//
#include <hip/hip_runtime.h>
#include <math.h>

#define BB 64
#define WW 128
#define FF 64
#define HH 4
#define OW 128

// ---------------------------------------------------------------------------
// Kernel 1: projections as pure LDS-resident GEMM.
// Grid 1024 = b(64) x rt(16): rows rt*64..+63 of concat [Wsrc(512);Wdst(512)].
// Stage x[b] ([k][f], direct copy, 32 KB) + W tile ([64 r][132], 33.8 KB).
// 16x16 threads, 4x4 register tile; inner loop = LDS b128 + FMA only,
// fully unrolled, zero barriers, zero global access.
// Output layout: fs/fd [B][H][node f][d] (node-major).
// ---------------------------------------------------------------------------
__global__ __launch_bounds__(256) void gat_proj(
    const float* __restrict__ x,     // [B][128 k][64 f]
    const float* __restrict__ Wsrc,  // [512][128]
    const float* __restrict__ bsrc,
    const float* __restrict__ Wdst,
    const float* __restrict__ bdst,
    float* __restrict__ fs,          // [B][H][64][128]
    float* __restrict__ fd)          // [B][H][64][128]
{
    __shared__ float xl[WW * FF];        // 32 KB [k][f]
    __shared__ float wl[64 * 132];       // 33.8 KB [r][k], pad 132
    __shared__ float bl[64];

    const int b  = blockIdx.x >> 4;
    const int rt = blockIdx.x & 15;
    const bool is_src = rt < 8;
    const int rm0 = (rt & 7) * 64;       // row base within the 512-row matrix

    const float* Wm = is_src ? Wsrc : Wdst;
    const float* bm = is_src ? bsrc : bdst;

    const int t = threadIdx.x;

    // ---- stage x (direct), W tile (padded rows), bias ----
    {
        const float4* xs = (const float4*)(x + (size_t)b * (WW * FF));
        float4* xd = (float4*)xl;
        #pragma unroll
        for (int p = 0; p < 8; ++p)
            xd[p * 256 + t] = xs[p * 256 + t];

        const float4* ws = (const float4*)(Wm + (size_t)rm0 * WW);
        float4* wd = (float4*)wl;
        #pragma unroll
        for (int p = 0; p < 8; ++p) {
            int idx = p * 256 + t;           // [r 64][kq 32]
            int r = idx >> 5, kq = idx & 31;
            wd[r * 33 + kq] = ws[idx];
        }
        if (t < 64) bl[t] = bm[rm0 + t];
    }
    __syncthreads();

    const int f0 = (t & 15) * 4;
    const int r0 = (t >> 4) * 4;

    float acc[4][4] = {};                    // [rr][ff]
    #pragma unroll
    for (int k0 = 0; k0 < WW; k0 += 4) {
        float4 xv[4], wv[4];
        #pragma unroll
        for (int kk = 0; kk < 4; ++kk)
            xv[kk] = *(const float4*)&xl[(k0 + kk) * FF + f0];
        #pragma unroll
        for (int rr = 0; rr < 4; ++rr)
            wv[rr] = *(const float4*)&wl[(r0 + rr) * 132 + k0];
        #pragma unroll
        for (int kk = 0; kk < 4; ++kk) {
            #pragma unroll
            for (int rr = 0; rr < 4; ++rr) {
                const float wf = ((const float*)&wv[rr])[kk];
                const float* xf = (const float*)&xv[kk];
                acc[rr][0] = fmaf(xf[0], wf, acc[rr][0]);
                acc[rr][1] = fmaf(xf[1], wf, acc[rr][1]);
                acc[rr][2] = fmaf(xf[2], wf, acc[rr][2]);
                acc[rr][3] = fmaf(xf[3], wf, acc[rr][3]);
            }
        }
    }

    // ---- epilogue: bias + store [b][h][f][d] ----
    const int h  = (rt & 7) >> 1;
    const int d0 = ((rt & 1) * 64) + r0;     // d contiguous across rr
    float* dst = (is_src ? fs : fd) + (((size_t)b * HH + h) * FF) * OW;
    float b0 = bl[r0 + 0], b1 = bl[r0 + 1], b2 = bl[r0 + 2], b3 = bl[r0 + 3];
    #pragma unroll
    for (int ff = 0; ff < 4; ++ff) {
        float4 o;
        o.x = acc[0][ff] + b0;
        o.y = acc[1][ff] + b1;
        o.z = acc[2][ff] + b2;
        o.w = acc[3][ff] + b3;
        *(float4*)&dst[(size_t)(f0 + ff) * OW + d0] = o;
    }
}

// ---------------------------------------------------------------------------
// Kernel 2: scores + edge-softmax + aggregation, all-LDS inner loops.
// Grid 1024 = (b, h, jq of 16 j). Block 256 = 4 waves. LDS ~50 KB -> 3/CU.
// fsl [i 64][132]: conflict-free for BOTH per-lane-i b128 (phase 1) and
// per-lane-d b32/b64 (phase 3) since 132%32=4, 33%32=1.
// St [i 64][20]: scores transposed so phase-3 P reads are b128 (j minor).
// ---------------------------------------------------------------------------
__global__ __launch_bounds__(256) void gat_attn(
    const float* __restrict__ fs,    // [B][H][64 i][128 d]
    const float* __restrict__ fd,    // [B][H][64 j][128 d]
    const float* __restrict__ attn,  // [H][128]
    float* __restrict__ ws2)         // [B][H][64 j][128 d]
{
    __shared__ float fsl[FF * 132];      // 33.8 KB [i][d] pad 132
    __shared__ float fdl[16 * OW];       // 8 KB    [jl][d]
    __shared__ float St[FF * 20];        // 5 KB    [i][jl] pad 20
    __shared__ float A6[OW], B4[OW];     // 1 KB
    __shared__ float redm[16][16];       // 1 KB
    __shared__ float reds[16][16];       // 1 KB
    __shared__ float invl[16];

    const int bx = blockIdx.x;
    const int jq = bx & 3;
    const int h  = (bx >> 2) & 3;
    const int b  = bx >> 4;
    const size_t bh = (size_t)b * HH + h;
    const int jbase = jq * 16;

    const int t    = threadIdx.x;
    const int wv   = t >> 6;
    const int lane = t & 63;

    // ---- stage fs slice, fd rows, folded attn coefficients ----
    {
        const float4* s = (const float4*)(fs + bh * (FF * OW));
        float4* d4 = (float4*)fsl;
        #pragma unroll
        for (int p = 0; p < 8; ++p) {
            int idx = p * 256 + t;           // [i 64][kq 32]
            int i = idx >> 5, kq = idx & 31;
            d4[i * 33 + kq] = s[idx];
        }
        const float4* fsrc = (const float4*)(fd + (bh * FF + jbase) * OW);
        float4* fdst = (float4*)fdl;
        fdst[t]       = fsrc[t];
        fdst[t + 256] = fsrc[t + 256];
        if (t < 128) {
            float a = attn[h * OW + t];
            A6[t] = 0.6f * a;
            B4[t] = 0.4f * a;
        }
    }
    __syncthreads();

    // ---- phase 1: scores; lane = i, wave covers j = jbase + wv*4 .. +3 ----
    const int jl0 = wv * 4;
    {
        float sc[4] = {0.0f, 0.0f, 0.0f, 0.0f};
        #pragma unroll
        for (int c = 0; c < 32; ++c) {
            const int d0 = c * 4;
            float4 fsv = *(const float4*)&fsl[lane * 132 + d0];   // per-lane b128
            float4 a6  = *(const float4*)&A6[d0];                 // bcast
            float4 b4  = *(const float4*)&B4[d0];
            #pragma unroll
            for (int jj = 0; jj < 4; ++jj) {
                float4 fdv = *(const float4*)&fdl[(jl0 + jj) * OW + d0]; // bcast
                float s, r = sc[jj];
                s = fsv.x + fdv.x; r = fmaf(a6.x, s, fmaf(b4.x, fabsf(s), r));
                s = fsv.y + fdv.y; r = fmaf(a6.y, s, fmaf(b4.y, fabsf(s), r));
                s = fsv.z + fdv.z; r = fmaf(a6.z, s, fmaf(b4.z, fabsf(s), r));
                s = fsv.w + fdv.w; r = fmaf(a6.w, s, fmaf(b4.w, fabsf(s), r));
                sc[jj] = r;
            }
        }
        float4 o = {sc[0], sc[1], sc[2], sc[3]};
        *(float4*)&St[lane * 20 + jl0] = o;      // [i][jl], aligned, 2-way max
    }
    __syncthreads();

    // ---- phase 2: softmax over i per column j (strips of 4 i) ----
    {
        const int j = t & 15, st = t >> 4;
        const int i0 = st * 4;
        float m0 = St[(i0 + 0) * 20 + j];
        float m1 = St[(i0 + 1) * 20 + j];
        float m2 = St[(i0 + 2) * 20 + j];
        float m3 = St[(i0 + 3) * 20 + j];
        redm[st][j] = fmaxf(fmaxf(m0, m1), fmaxf(m2, m3));
    }
    __syncthreads();
    {
        const int j = t & 15, st = t >> 4;
        const int i0 = st * 4;
        float mj = redm[0][j];
        #pragma unroll
        for (int s2 = 1; s2 < 16; ++s2) mj = fmaxf(mj, redm[s2][j]);
        float e0 = __expf(St[(i0 + 0) * 20 + j] - mj);
        float e1 = __expf(St[(i0 + 1) * 20 + j] - mj);
        float e2 = __expf(St[(i0 + 2) * 20 + j] - mj);
        float e3 = __expf(St[(i0 + 3) * 20 + j] - mj);
        St[(i0 + 0) * 20 + j] = e0;
        St[(i0 + 1) * 20 + j] = e1;
        St[(i0 + 2) * 20 + j] = e2;
        St[(i0 + 3) * 20 + j] = e3;
        reds[st][j] = e0 + e1 + e2 + e3;
    }
    __syncthreads();
    if (t < 16) {
        float l = 0.0f;
        #pragma unroll
        for (int s2 = 0; s2 < 16; ++s2) l += reds[s2][t];
        invl[t] = 0.25f / l;                     // head-mean folded
    }
    __syncthreads();

    // ---- phase 3: aggregation; thread = (4 j, 2 d), all-LDS ----
    {
        const int j0 = (t & 3) * 4;              // 4 j
        const int d0 = (t >> 2) * 2;             // 2 d
        float ag[4][2] = {};
        #pragma unroll
        for (int i = 0; i < FF; ++i) {
            float4 pv = *(const float4*)&St[i * 20 + j0];     // b128, <=4-way
            float2 fv = *(const float2*)&fsl[i * 132 + d0];   // b64, spread
            const float* pf = (const float*)&pv;
            #pragma unroll
            for (int jj = 0; jj < 4; ++jj) {
                ag[jj][0] = fmaf(pf[jj], fv.x, ag[jj][0]);
                ag[jj][1] = fmaf(pf[jj], fv.y, ag[jj][1]);
            }
        }
        float* wout = ws2 + (bh * FF + jbase) * OW;
        #pragma unroll
        for (int jj = 0; jj < 4; ++jj) {
            float ivv = invl[j0 + jj];
            float2 o = {ag[jj][0] * ivv, ag[jj][1] * ivv};
            *(float2*)&wout[(size_t)(j0 + jj) * OW + d0] = o;  // coalesced f2
        }
    }
}

// ---------------------------------------------------------------------------
// Kernel 3: head-sum + transpose -> out[b][d][f]. Grid 256 = (b, jg of 16).
// ---------------------------------------------------------------------------
__global__ __launch_bounds__(256) void gat_reduce(
    const float* __restrict__ ws2,   // [B][H][64 j][128 d]
    float* __restrict__ out)         // [B][128 d][64 f]
{
    __shared__ float tl[16][132];
    const int b  = blockIdx.x >> 2;
    const int jg = blockIdx.x & 3;
    const int t  = threadIdx.x;

    const float* base = ws2 + ((size_t)b * HH * FF + jg * 16) * OW;
    #pragma unroll
    for (int p = 0; p < 2; ++p) {
        int idx = p * 256 + t;               // float4 idx in [16 j][32 q]
        int j = idx >> 5, q = idx & 31;
        const float* src = base + (size_t)j * OW + q * 4;
        float4 s0 = *(const float4*)(src);
        float4 s1 = *(const float4*)(src + (size_t)FF * OW);
        float4 s2 = *(const float4*)(src + (size_t)2 * FF * OW);
        float4 s3 = *(const float4*)(src + (size_t)3 * FF * OW);
        float4 o;
        o.x = s0.x + s1.x + s2.x + s3.x;
        o.y = s0.y + s1.y + s2.y + s3.y;
        o.z = s0.z + s1.z + s2.z + s3.z;
        o.w = s0.w + s1.w + s2.w + s3.w;
        *(float4*)&tl[j][q * 4] = o;
    }
    __syncthreads();
    #pragma unroll
    for (int it = 0; it < 8; ++it) {
        int idx = it * 256 + t;
        int j = idx & 15, d = idx >> 4;
        out[((size_t)b * OW + d) * FF + jg * 16 + j] = tl[j][d];
    }
}

// ---------------------------------------------------------------------------
extern "C" void kernel_launch(void* const* d_in, const int* in_sizes, int n_in,
                              void* d_out, int out_size, void* d_ws, size_t ws_size,
                              hipStream_t stream) {
    const float* x    = (const float*)d_in[0];
    const float* Wsrc = (const float*)d_in[1];
    const float* bsrc = (const float*)d_in[2];
    const float* Wdst = (const float*)d_in[3];
    const float* bdst = (const float*)d_in[4];
    const float* attn = (const float*)d_in[5];
    float* out = (float*)d_out;

    const size_t SL = (size_t)BB * HH * FF * OW;      // 2M floats = 8 MB
    float* fs  = (float*)d_ws;
    float* fd  = fs + SL;
    float* ws2 = fd + SL;

    gat_proj  <<<BB * 16,     256, 0, stream>>>(x, Wsrc, bsrc, Wdst, bdst, fs, fd);
    gat_attn  <<<BB * HH * 4, 256, 0, stream>>>(fs, fd, attn, ws2);
    gat_reduce<<<BB * 4,      256, 0, stream>>>(ws2, out);
}

// Round 7
// 115.501 us; speedup vs baseline: 1.4225x; 1.0180x over previous
//
#include <hip/hip_runtime.h>
#include <math.h>

#define BB 64
#define WW 128
#define FF 64
#define HH 4
#define OW 128

// ---------------------------------------------------------------------------
// Kernel 1: projections, LDS-resident GEMM, K split in two 64-wide phases.
// LDS 33.4 KB -> 4 blocks/CU, grid 1024 fully resident (16 waves/CU).
// Grid = b(64) x rt(16): rows rt*64..+63 of concat [Wsrc(512);Wdst(512)].
// 16x16 threads, 4x4 register tile; inner loop = LDS b128 + FMA only.
// Output layout: fs/fd [B][H][node][d].
// ---------------------------------------------------------------------------
__global__ __launch_bounds__(256) void gat_proj(
    const float* __restrict__ x,     // [B][128 k][64 f]
    const float* __restrict__ Wsrc,  // [512][128]
    const float* __restrict__ bsrc,
    const float* __restrict__ Wdst,
    const float* __restrict__ bdst,
    float* __restrict__ fs,          // [B][H][64][128]
    float* __restrict__ fd)          // [B][H][64][128]
{
    __shared__ float xl[64 * FF];        // 16 KB [k_half][f]
    __shared__ float wl[64 * 68];        // 17 KB [r][k_half], pad 68
    __shared__ float bl[64];

    const int b  = blockIdx.x >> 4;
    const int rt = blockIdx.x & 15;
    const bool is_src = rt < 8;
    const int rm0 = (rt & 7) * 64;       // row base within the 512-row matrix

    const float* Wm = is_src ? Wsrc : Wdst;
    const float* bm = is_src ? bsrc : bdst;

    const int t  = threadIdx.x;
    const int f0 = (t & 15) * 4;
    const int r0 = (t >> 4) * 4;

    float acc[4][4] = {};                // [rr][ff]

    for (int kp = 0; kp < 2; ++kp) {
        // ---- stage x half (64k x 64f = 16 KB) ----
        {
            const float4* xs = (const float4*)(x + (size_t)b * (WW * FF) + kp * 64 * FF);
            float4* xd = (float4*)xl;
            #pragma unroll
            for (int p = 0; p < 4; ++p)
                xd[p * 256 + t] = xs[p * 256 + t];
            // ---- stage W half: 64 rows x 64 cols ----
            float4* wd = (float4*)wl;            // row stride 17 f4
            #pragma unroll
            for (int p = 0; p < 4; ++p) {
                int idx = p * 256 + t;           // [r 64][kq 16]
                int r = idx >> 4, kq = idx & 15;
                wd[r * 17 + kq] =
                    *(const float4*)(Wm + (size_t)(rm0 + r) * WW + kp * 64 + kq * 4);
            }
            if (kp == 0 && t < 64) bl[t] = bm[rm0 + t];
        }
        __syncthreads();

        #pragma unroll
        for (int k0 = 0; k0 < 64; k0 += 4) {
            float4 xv[4], wv[4];
            #pragma unroll
            for (int kk = 0; kk < 4; ++kk)
                xv[kk] = *(const float4*)&xl[(k0 + kk) * FF + f0];
            #pragma unroll
            for (int rr = 0; rr < 4; ++rr)
                wv[rr] = *(const float4*)&wl[(r0 + rr) * 68 + k0];   // 16-lane bcast
            #pragma unroll
            for (int kk = 0; kk < 4; ++kk) {
                #pragma unroll
                for (int rr = 0; rr < 4; ++rr) {
                    const float wf = ((const float*)&wv[rr])[kk];
                    const float* xf = (const float*)&xv[kk];
                    acc[rr][0] = fmaf(xf[0], wf, acc[rr][0]);
                    acc[rr][1] = fmaf(xf[1], wf, acc[rr][1]);
                    acc[rr][2] = fmaf(xf[2], wf, acc[rr][2]);
                    acc[rr][3] = fmaf(xf[3], wf, acc[rr][3]);
                }
            }
        }
        __syncthreads();
    }

    // ---- epilogue: bias + store [b][h][f][d] ----
    const int h  = (rt & 7) >> 1;
    const int d0 = ((rt & 1) * 64) + r0;
    float* dst = (is_src ? fs : fd) + (((size_t)b * HH + h) * FF) * OW;
    float b0 = bl[r0 + 0], b1 = bl[r0 + 1], b2 = bl[r0 + 2], b3 = bl[r0 + 3];
    #pragma unroll
    for (int ff = 0; ff < 4; ++ff) {
        float4 o;
        o.x = acc[0][ff] + b0;
        o.y = acc[1][ff] + b1;
        o.z = acc[2][ff] + b2;
        o.w = acc[3][ff] + b3;
        *(float4*)&dst[(size_t)(f0 + ff) * OW + d0] = o;
    }
}

// ---------------------------------------------------------------------------
// Kernel 2: scores + edge-softmax + aggregation, all-LDS inner loops.
// Grid 512 = (b, h, jh of 32 j) -> 2 blocks/CU exactly, no tail. LDS 63.5 KB.
// score[i][j] = cs_i + cd_j + sum_d 0.4a_d * |fs[i,d]+fd[j,d]|   (2 ops/elem)
// with cs_i = sum_d 0.6a_d fs[i,d], cd_j likewise (precomputed, trivial).
// All LDS patterns <=2-way: rows padded to 132 (9 quads == 1 mod 8), St
// padded to 36.
// ---------------------------------------------------------------------------
__global__ __launch_bounds__(256) void gat_attn(
    const float* __restrict__ fs,    // [B][H][64 i][128 d]
    const float* __restrict__ fd,    // [B][H][64 j][128 d]
    const float* __restrict__ attn,  // [H][128]
    float* __restrict__ ws2)         // [B][H][64 j][128 d]
{
    __shared__ float fsl[FF * 132];      // 33.8 KB [i][d] pad 132
    __shared__ float fdl[32 * 132];      // 16.9 KB [jl][d] pad 132
    __shared__ float St[FF * 36];        // 9.2 KB [i][jl] pad 36
    __shared__ float A6[OW], B4[OW];     // 1 KB
    __shared__ float cs[FF], cd[32];
    __shared__ float redm[8][32];        // 1 KB
    __shared__ float reds[8][32];        // 1 KB
    __shared__ float invl[32];

    const int bx = blockIdx.x;
    const int jh = bx & 1;
    const int h  = (bx >> 1) & 3;
    const int b  = bx >> 3;
    const size_t bh = (size_t)b * HH + h;
    const int jbase = jh * 32;

    const int t    = threadIdx.x;
    const int wv   = t >> 6;
    const int lane = t & 63;

    // ---- stage fsl (2048 f4), fdl (1024 f4), attn coefficients ----
    {
        const float4* s = (const float4*)(fs + bh * (FF * OW));
        float4* d4 = (float4*)fsl;           // row stride 33 f4
        #pragma unroll
        for (int p = 0; p < 8; ++p) {
            int idx = p * 256 + t;
            int i = idx >> 5, kq = idx & 31;
            d4[i * 33 + kq] = s[idx];
        }
        const float4* fsrc = (const float4*)(fd + (bh * FF + jbase) * OW);
        float4* fdst = (float4*)fdl;         // row stride 33 f4
        #pragma unroll
        for (int p = 0; p < 4; ++p) {
            int idx = p * 256 + t;
            int j = idx >> 5, kq = idx & 31;
            fdst[j * 33 + kq] = fsrc[idx];
        }
        if (t < 128) {
            float a = attn[h * OW + t];
            A6[t] = 0.6f * a;
            B4[t] = 0.4f * a;
        }
    }
    __syncthreads();

    // ---- cs_i (threads 0-63) and cd_j (threads 64-95) ----
    if (t < 64) {
        float s = 0.0f;
        #pragma unroll 8
        for (int c = 0; c < 32; ++c) {
            float4 fv = *(const float4*)&fsl[t * 132 + c * 4];
            float4 av = *(const float4*)&A6[c * 4];
            s = fmaf(fv.x, av.x, fmaf(fv.y, av.y, fmaf(fv.z, av.z, fmaf(fv.w, av.w, s))));
        }
        cs[t] = s;
    } else if (t < 96) {
        const int j = t - 64;
        float s = 0.0f;
        #pragma unroll 8
        for (int c = 0; c < 32; ++c) {
            float4 fv = *(const float4*)&fdl[j * 132 + c * 4];
            float4 av = *(const float4*)&A6[c * 4];
            s = fmaf(fv.x, av.x, fmaf(fv.y, av.y, fmaf(fv.z, av.z, fmaf(fv.w, av.w, s))));
        }
        cd[j] = s;
    }
    __syncthreads();

    // ---- phase 1: |s| partial scores; lane = i, wave covers 8 j ----
    const int jl0 = wv * 8;
    {
        float sc[8] = {};
        #pragma unroll 4
        for (int c = 0; c < 32; ++c) {
            const int d0 = c * 4;
            float4 fsv = *(const float4*)&fsl[lane * 132 + d0];   // per-lane b128
            float4 b4  = *(const float4*)&B4[d0];                 // bcast
            #pragma unroll
            for (int jj = 0; jj < 8; ++jj) {
                float4 fdv = *(const float4*)&fdl[(jl0 + jj) * 132 + d0]; // bcast
                float r = sc[jj];
                r = fmaf(b4.x, fabsf(fsv.x + fdv.x), r);
                r = fmaf(b4.y, fabsf(fsv.y + fdv.y), r);
                r = fmaf(b4.z, fabsf(fsv.z + fdv.z), r);
                r = fmaf(b4.w, fabsf(fsv.w + fdv.w), r);
                sc[jj] = r;
            }
        }
        const float csl = cs[lane];
        float4 o0, o1;
        o0.x = sc[0] + csl + cd[jl0 + 0];
        o0.y = sc[1] + csl + cd[jl0 + 1];
        o0.z = sc[2] + csl + cd[jl0 + 2];
        o0.w = sc[3] + csl + cd[jl0 + 3];
        o1.x = sc[4] + csl + cd[jl0 + 4];
        o1.y = sc[5] + csl + cd[jl0 + 5];
        o1.z = sc[6] + csl + cd[jl0 + 6];
        o1.w = sc[7] + csl + cd[jl0 + 7];
        *(float4*)&St[lane * 36 + jl0]     = o0;   // stride 36: conflict-free
        *(float4*)&St[lane * 36 + jl0 + 4] = o1;
    }
    __syncthreads();

    // ---- phase 2: softmax over i per column j (8 strips of 8 i) ----
    {
        const int j = t & 31, st = t >> 5;
        const int i0 = st * 8;
        float m = St[i0 * 36 + j];
        #pragma unroll
        for (int k = 1; k < 8; ++k) m = fmaxf(m, St[(i0 + k) * 36 + j]);
        redm[st][j] = m;
    }
    __syncthreads();
    {
        const int j = t & 31, st = t >> 5;
        const int i0 = st * 8;
        float mj = redm[0][j];
        #pragma unroll
        for (int s2 = 1; s2 < 8; ++s2) mj = fmaxf(mj, redm[s2][j]);
        float ps = 0.0f;
        #pragma unroll
        for (int k = 0; k < 8; ++k) {
            float e = __expf(St[(i0 + k) * 36 + j] - mj);
            St[(i0 + k) * 36 + j] = e;
            ps += e;
        }
        reds[st][j] = ps;
    }
    __syncthreads();
    if (t < 32) {
        float l = 0.0f;
        #pragma unroll
        for (int s2 = 0; s2 < 8; ++s2) l += reds[s2][t];
        invl[t] = 0.25f / l;                 // head-mean folded
    }
    __syncthreads();

    // ---- phase 3: aggregation; thread = (j = t>>3, dg = t&7), 16 d each ----
    // d set = {32q + dg*4 + e}: fsl b128 quads = (i*33 + dg) % 8 -> 8 distinct.
    {
        const int dg = t & 7;
        const int jr = t >> 3;
        float ag[16] = {};
        for (int i = 0; i < FF; ++i) {
            const float p = St[i * 36 + jr];            // 8-lane bcast groups
            const float* fr = &fsl[i * 132 + dg * 4];
            float4 f0 = *(const float4*)(fr);
            float4 f1 = *(const float4*)(fr + 32);
            float4 f2 = *(const float4*)(fr + 64);
            float4 f3 = *(const float4*)(fr + 96);
            ag[0]  = fmaf(p, f0.x, ag[0]);  ag[1]  = fmaf(p, f0.y, ag[1]);
            ag[2]  = fmaf(p, f0.z, ag[2]);  ag[3]  = fmaf(p, f0.w, ag[3]);
            ag[4]  = fmaf(p, f1.x, ag[4]);  ag[5]  = fmaf(p, f1.y, ag[5]);
            ag[6]  = fmaf(p, f1.z, ag[6]);  ag[7]  = fmaf(p, f1.w, ag[7]);
            ag[8]  = fmaf(p, f2.x, ag[8]);  ag[9]  = fmaf(p, f2.y, ag[9]);
            ag[10] = fmaf(p, f2.z, ag[10]); ag[11] = fmaf(p, f2.w, ag[11]);
            ag[12] = fmaf(p, f3.x, ag[12]); ag[13] = fmaf(p, f3.y, ag[13]);
            ag[14] = fmaf(p, f3.z, ag[14]); ag[15] = fmaf(p, f3.w, ag[15]);
        }
        const float iv = invl[jr];
        float* wout = ws2 + (bh * FF + jbase + jr) * OW + dg * 4;
        #pragma unroll
        for (int q = 0; q < 4; ++q) {
            float4 o;
            o.x = ag[q * 4 + 0] * iv;
            o.y = ag[q * 4 + 1] * iv;
            o.z = ag[q * 4 + 2] * iv;
            o.w = ag[q * 4 + 3] * iv;
            *(float4*)&wout[q * 32] = o;    // 128B segments per (j,q)
        }
    }
}

// ---------------------------------------------------------------------------
// Kernel 3: head-sum + transpose -> out[b][d][f]. Grid 256 = (b, jg of 16).
// ---------------------------------------------------------------------------
__global__ __launch_bounds__(256) void gat_reduce(
    const float* __restrict__ ws2,   // [B][H][64 j][128 d]
    float* __restrict__ out)         // [B][128 d][64 f]
{
    __shared__ float tl[16][132];
    const int b  = blockIdx.x >> 2;
    const int jg = blockIdx.x & 3;
    const int t  = threadIdx.x;

    const float* base = ws2 + ((size_t)b * HH * FF + jg * 16) * OW;
    #pragma unroll
    for (int p = 0; p < 2; ++p) {
        int idx = p * 256 + t;               // float4 idx in [16 j][32 q]
        int j = idx >> 5, q = idx & 31;
        const float* src = base + (size_t)j * OW + q * 4;
        float4 s0 = *(const float4*)(src);
        float4 s1 = *(const float4*)(src + (size_t)FF * OW);
        float4 s2 = *(const float4*)(src + (size_t)2 * FF * OW);
        float4 s3 = *(const float4*)(src + (size_t)3 * FF * OW);
        float4 o;
        o.x = s0.x + s1.x + s2.x + s3.x;
        o.y = s0.y + s1.y + s2.y + s3.y;
        o.z = s0.z + s1.z + s2.z + s3.z;
        o.w = s0.w + s1.w + s2.w + s3.w;
        *(float4*)&tl[j][q * 4] = o;
    }
    __syncthreads();
    #pragma unroll
    for (int it = 0; it < 8; ++it) {
        int idx = it * 256 + t;
        int j = idx & 15, d = idx >> 4;
        out[((size_t)b * OW + d) * FF + jg * 16 + j] = tl[j][d];
    }
}

// ---------------------------------------------------------------------------
extern "C" void kernel_launch(void* const* d_in, const int* in_sizes, int n_in,
                              void* d_out, int out_size, void* d_ws, size_t ws_size,
                              hipStream_t stream) {
    const float* x    = (const float*)d_in[0];
    const float* Wsrc = (const float*)d_in[1];
    const float* bsrc = (const float*)d_in[2];
    const float* Wdst = (const float*)d_in[3];
    const float* bdst = (const float*)d_in[4];
    const float* attn = (const float*)d_in[5];
    float* out = (float*)d_out;

    const size_t SL = (size_t)BB * HH * FF * OW;      // 2M floats = 8 MB
    float* fs  = (float*)d_ws;
    float* fd  = fs + SL;
    float* ws2 = fd + SL;

    gat_proj  <<<BB * 16,     256, 0, stream>>>(x, Wsrc, bsrc, Wdst, bdst, fs, fd);
    gat_attn  <<<BB * HH * 2, 256, 0, stream>>>(fs, fd, attn, ws2);
    gat_reduce<<<BB * 4,      256, 0, stream>>>(ws2, out);
}